// Round 1
// baseline (551.818 us; speedup 1.0000x reference)
//
#include <hip/hip_runtime.h>
#include <hip/hip_bf16.h>
#include <stdint.h>

#define T_ROWS 131072
#define GCNT   64
#define KDIM   1024
#define NDIM   512
#define BM     128
#define BN     128
#define BK     64
#define KTILES (KDIM / BK)            // 16
#define NTILES (NDIM / BN)            // 4
#define MT_MAX (T_ROWS / BM + GCNT)   // 1088 upper bound on padded M-tiles
#define APAD   72                     // BK + 8 bf16 elems -> 144B rows, 2-way max

typedef __attribute__((ext_vector_type(4))) float f32x4;
typedef __attribute__((ext_vector_type(8))) short s16x8;
typedef __attribute__((address_space(3))) unsigned int lds_u32;
typedef const __attribute__((address_space(1))) unsigned int gbl_u32;

static __device__ __forceinline__ short f2bf(float f) {
  __hip_bfloat16 h = __float2bfloat16(f);
  return __builtin_bit_cast(short, h);
}

// ---------------------------------------------------------------------------
// Pre-pass: b [G][K][N] fp32  ->  bt: per (g, nt, kt) 16KB bf16 tile images,
// layout [G][NTILES][KTILES][16384B]. Image byte for value B[k][n] (k in
// [0,64), n in [0,128)):  n*128 + (((k>>3) ^ (n&7))<<4) + (k&7)*2
// (XOR slot swizzle baked in so GEMM-side ds_read_b128 is ~conflict-free).
// ---------------------------------------------------------------------------
__global__ __launch_bounds__(256) void bt_kernel(const float* __restrict__ b,
                                                 char* __restrict__ bt) {
  __shared__ short lt[64 * 130];      // [k][n] tile, pad 128->130 (2-way reads)
  int bid = blockIdx.x;               // g*64 + nt*16 + kt
  int kt = bid & 15, nt = (bid >> 4) & 3, g = bid >> 6;
  int t = threadIdx.x;
  const float* src = b + ((size_t)(g * KDIM + kt * BK)) * NDIM + nt * BN;
#pragma unroll
  for (int i = 0; i < 32; i++) {
    int idx = i * 256 + t;
    int kk = idx >> 7, nn = idx & 127;
    lt[kk * 130 + nn] = f2bf(src[(size_t)kk * NDIM + nn]);
  }
  __syncthreads();
  char* dst = bt + ((size_t)bid << 14);
#pragma unroll
  for (int j = 0; j < 4; j++) {
    int chunk = j * 256 + t;          // 16B chunk index in image
    int n = chunk >> 3;
    int slot = (chunk & 7) ^ (n & 7); // un-swizzle to find source k-range
    s16x8 v;
#pragma unroll
    for (int i = 0; i < 8; i++) v[i] = lt[(slot * 8 + i) * 130 + n];
    *(s16x8*)(dst + (size_t)chunk * 16) = v;
  }
}

// ---------------------------------------------------------------------------
// Grouped GEMM: 128x128 tile, 4 waves (2x2), BK=64, double-buffered LDS,
// mfma_f32_16x16x32_bf16, A reg-staged fp32->bf16, B via global_load_lds
// from the pre-swizzled image (or reg-staged transpose fallback).
// ---------------------------------------------------------------------------
template <bool USE_BT>
__global__ __launch_bounds__(256, 2) void gemm_kernel(
    const float* __restrict__ a, const float* __restrict__ b,
    const char* __restrict__ bt, const int* __restrict__ sizes,
    const int* __restrict__ offs, const int* __restrict__ poffs,
    float* __restrict__ out) {
  __shared__ __align__(16) short lds_a[2][BM * APAD];
  __shared__ __align__(16) char lds_b[2][BN * BK * 2];

  int bid = blockIdx.x;
  int bn = bid & 3;
  int tm = bid >> 2;
  int m128 = tm * BM;

  // uniform scan: which group does this padded tile belong to
  int g = 0;
#pragma unroll
  for (int i = 1; i < GCNT; i++)
    if (poffs[i] <= m128) g = i;
  int size = sizes[g];
  int m_loc = m128 - poffs[g];
  if (m_loc >= ((size + 127) & ~127)) return;  // beyond total padded rows
  int off = offs[g];
  int valid = size - m_loc;

  int t = threadIdx.x;
  int lane = t & 63;
  int wid = t >> 6;
  int wm = wid >> 1, wn = wid & 1;

  // --- A staging coords: thread t loads row (t>>1), k-half (t&1)*32 ---
  int ar = t >> 1;
  int ah = t & 1;
  int arow = off + m_loc + ar;
  if (arow >= T_ROWS) arow = T_ROWS - 1;  // rows >= valid are masked at store
  const float* aptr = a + (size_t)arow * KDIM + ah * 32;

  // --- B fallback coords: thread t owns column n=(t>>1), k-chunk (t&1)*32 ---
  int bnn = t >> 1;
  int bc0 = (t & 1) * 32;
  const float* bptr =
      b + (size_t)g * KDIM * NDIM + (size_t)bc0 * NDIM + bn * BN + bnn;

  const char* btbase = bt + (((size_t)(g * NTILES + bn)) << 18);  // *16*16384

  f32x4 acc[4][4];
#pragma unroll
  for (int i = 0; i < 4; i++)
#pragma unroll
    for (int j = 0; j < 4; j++) acc[i][j] = (f32x4){0.f, 0.f, 0.f, 0.f};

  float ar32[32];

  auto loadA = [&](int kt) {
    const float* p = aptr + kt * BK;
#pragma unroll
    for (int i = 0; i < 8; i++)
      *(f32x4*)(ar32 + i * 4) = *(const f32x4*)(p + i * 4);
  };
  auto writeA = [&](int c) {
    short* db = lds_a[c] + ar * APAD + ah * 32;
#pragma unroll
    for (int i2 = 0; i2 < 4; i2++) {
      s16x8 v;
#pragma unroll
      for (int e = 0; e < 8; e++) v[e] = f2bf(ar32[i2 * 8 + e]);
      *(s16x8*)(db + i2 * 8) = v;
    }
  };
  auto stageB_bt = [&](int kt, int c) {
    const char* gsrc = btbase + ((size_t)kt << 14) + wid * 4096 + lane * 16;
    char* lb = (char*)lds_b[c] + wid * 4096;
#pragma unroll
    for (int i = 0; i < 4; i++)
      __builtin_amdgcn_global_load_lds((gbl_u32*)(gsrc + i * 1024),
                                       (lds_u32*)(lb + i * 1024), 16, 0, 0);
  };
  auto stageB_fb = [&](int kt, int c) {
    const float* p = bptr + (size_t)kt * BK * NDIM;
    float vals[32];
#pragma unroll
    for (int i = 0; i < 32; i++) vals[i] = p[(size_t)i * NDIM];
    char* lb = (char*)lds_b[c];
#pragma unroll
    for (int i8 = 0; i8 < 4; i8++) {
      int slot = (bc0 >> 3) + i8;
      s16x8 v;
#pragma unroll
      for (int e = 0; e < 8; e++) v[e] = f2bf(vals[i8 * 8 + e]);
      *(s16x8*)(lb + bnn * 128 + ((slot ^ (bnn & 7)) << 4)) = v;
    }
  };

  // prologue: stage tile 0
  loadA(0);
  if (USE_BT) stageB_bt(0, 0);
  else stageB_fb(0, 0);
  writeA(0);
  __syncthreads();

  int cur = 0;
  for (int kt = 0; kt < KTILES; kt++) {
    if (kt + 1 < KTILES) {
      loadA(kt + 1);                        // issue next A loads early
      if (USE_BT) stageB_bt(kt + 1, cur ^ 1);  // async global->LDS, in flight
    }
    // compute current buffer
    {
      const short* As = lds_a[cur];
      const char* Bs = lds_b[cur];
#pragma unroll
      for (int ks = 0; ks < 2; ks++) {
        s16x8 af[4], bfr[4];
#pragma unroll
        for (int fm = 0; fm < 4; fm++)
          af[fm] = *(const s16x8*)(As + (wm * 64 + fm * 16 + (lane & 15)) * APAD +
                                   ks * 32 + (lane >> 4) * 8);
#pragma unroll
        for (int fn = 0; fn < 4; fn++) {
          int n = wn * 64 + fn * 16 + (lane & 15);
          int slot = (ks * 4 + (lane >> 4)) ^ (n & 7);
          bfr[fn] = *(const s16x8*)(Bs + n * 128 + slot * 16);
        }
#pragma unroll
        for (int fm = 0; fm < 4; fm++)
#pragma unroll
          for (int fn = 0; fn < 4; fn++)
            acc[fm][fn] = __builtin_amdgcn_mfma_f32_16x16x32_bf16(
                af[fm], bfr[fn], acc[fm][fn], 0, 0, 0);
      }
    }
    if (kt + 1 < KTILES) {
      if (!USE_BT) stageB_fb(kt + 1, cur ^ 1);
      writeA(cur ^ 1);                      // waits A loads, converts, ds_write
      __syncthreads();
      cur ^= 1;
    }
  }

  // epilogue: masked store. D frag: col = lane&15, row = (lane>>4)*4 + j
  float* obase =
      out + (size_t)(off + m_loc) * NDIM + bn * BN + wn * 64 + (lane & 15);
#pragma unroll
  for (int fm = 0; fm < 4; fm++) {
#pragma unroll
    for (int j = 0; j < 4; j++) {
      int rm = wm * 64 + fm * 16 + (lane >> 4) * 4 + j;
      if (rm < valid) {
#pragma unroll
        for (int fn = 0; fn < 4; fn++)
          obase[(size_t)rm * NDIM + fn * 16] = acc[fm][fn][j];
      }
    }
  }
}

extern "C" void kernel_launch(void* const* d_in, const int* in_sizes, int n_in,
                              void* d_out, int out_size, void* d_ws,
                              size_t ws_size, hipStream_t stream) {
  const float* a = (const float*)d_in[0];
  const float* b = (const float*)d_in[1];
  const int* sizes = (const int*)d_in[2];
  const int* offs = (const int*)d_in[3];
  const int* poffs = (const int*)d_in[4];
  float* out = (float*)d_out;

  const size_t bt_bytes = (size_t)GCNT * KDIM * NDIM * 2;  // 64 MB
  if (ws_size >= bt_bytes) {
    bt_kernel<<<GCNT * NTILES * KTILES, 256, 0, stream>>>(b, (char*)d_ws);
    gemm_kernel<true><<<MT_MAX * NTILES, 256, 0, stream>>>(
        a, b, (const char*)d_ws, sizes, offs, poffs, out);
  } else {
    gemm_kernel<false><<<MT_MAX * NTILES, 256, 0, stream>>>(
        a, b, (const char*)nullptr, sizes, offs, poffs, out);
  }
}

// Round 2
// 342.280 us; speedup vs baseline: 1.6122x; 1.6122x over previous
//
#include <hip/hip_runtime.h>
#include <hip/hip_bf16.h>
#include <stdint.h>

#define T_ROWS 131072
#define GCNT   64
#define KDIM   1024
#define NDIM   512
#define BM     256
#define BN     256
#define BK     64
#define KTILES (KDIM / BK)     // 16
#define MT_MAX 640             // safe upper bound on 256-row tiles (actual ~550)
#define NBLK   (MT_MAX * 2)    // 1280 blocks, divisible by 8 (XCD swizzle)

typedef __attribute__((ext_vector_type(4))) float f32x4;
typedef __attribute__((ext_vector_type(8))) short s16x8;
typedef __attribute__((ext_vector_type(4))) short s16x4;
typedef __attribute__((address_space(3))) unsigned int lds_u32;
typedef const __attribute__((address_space(1))) unsigned int gbl_u32;

static __device__ __forceinline__ short f2bf(float f) {
  __hip_bfloat16 h = __float2bfloat16(f);
  return __builtin_bit_cast(short, h);
}

// ---------------------------------------------------------------------------
// Pre-pass: b [G][K][N] fp32 -> bt: per (g, nt128, kt) 16KB bf16 tile images,
// layout [G][4][16][16384B]. Image byte for B[k][n] (k in [0,64), n in
// [0,128)):  n*128 + (((k>>3) ^ (n&7))<<4) + (k&7)*2   (bank swizzle baked).
// ---------------------------------------------------------------------------
__global__ __launch_bounds__(256) void bt_kernel(const float* __restrict__ b,
                                                 char* __restrict__ bt) {
  __shared__ short lt[64 * 130];
  int bid = blockIdx.x;               // g*64 + nt*16 + kt
  int kt = bid & 15, nt = (bid >> 4) & 3, g = bid >> 6;
  int t = threadIdx.x;
  const float* src = b + ((size_t)(g * KDIM + kt * BK)) * NDIM + nt * 128;
#pragma unroll
  for (int i = 0; i < 32; i++) {
    int idx = i * 256 + t;
    int kk = idx >> 7, nn = idx & 127;
    lt[kk * 130 + nn] = f2bf(src[(size_t)kk * NDIM + nn]);
  }
  __syncthreads();
  char* dst = bt + ((size_t)bid << 14);
#pragma unroll
  for (int j = 0; j < 4; j++) {
    int chunk = j * 256 + t;
    int n = chunk >> 3;
    int slot = (chunk & 7) ^ (n & 7);
    s16x8 v;
#pragma unroll
    for (int i = 0; i < 8; i++) v[i] = lt[(slot * 8 + i) * 130 + n];
    *(s16x8*)(dst + (size_t)chunk * 16) = v;
  }
}

// ---------------------------------------------------------------------------
// Grouped GEMM: 256x256 tile, 8 waves (2M x 4N), BK=64, double-buffered LDS,
// A fp32 reg-staged -> bf16 (XOR-swizzled LDS), B via global_load_lds from
// pre-swizzled image. 2-phase pipeline, one barrier per K-step.
// ---------------------------------------------------------------------------
template <bool USE_BT>
__global__ __launch_bounds__(512, 2) void gemm_kernel(
    const float* __restrict__ a, const float* __restrict__ b,
    const char* __restrict__ bt, const int* __restrict__ sizes,
    const int* __restrict__ offs, float* __restrict__ out) {
  __shared__ __align__(16) short lds_a[2][BM * BK];     // 2 x 32 KB
  __shared__ __align__(16) char lds_b[2][BN * BK * 2];  // 2 x 32 KB

  // XCD-chunked swizzle: consecutive logical blocks land on the same XCD.
  int bid0 = blockIdx.x;
  int bid = (bid0 & 7) * (NBLK / 8) + (bid0 >> 3);
  int bn = bid & 1;        // bn fastest: the A-sharing pair is L2-adjacent
  int tm = bid >> 1;

  // group scan: tiles_g = ceil(padded_size_g / 256)
  int g = -1, m_loc = 0, base = 0;
#pragma unroll
  for (int i = 0; i < GCNT; i++) {
    int ps = (sizes[i] + 127) & ~127;
    int tg = (ps + 255) >> 8;
    if (tm >= base && tm < base + tg) { g = i; m_loc = (tm - base) << 8; }
    base += tg;
  }
  if (g < 0) return;
  int size = sizes[g];
  int off = offs[g];
  int valid = size - m_loc;

  int t = threadIdx.x;
  int lane = t & 63;
  int wid = t >> 6;
  int wm = wid >> 2, wn = wid & 3;
  int lr = lane & 15, q = lane >> 4;

  // --- A staging: thread t owns fp32 16B chunks c = i*512 + t, i in [0,8) ---
  // row_in_tile = i*32 + (t>>4), fp32 col = (t&15)*4. Fully coalesced loads.
  int r0 = t >> 4;          // 0..31
  int c16 = t & 15;         // 16B chunk within row
  int aoff[8];
#pragma unroll
  for (int i = 0; i < 8; i++) {
    int row = off + m_loc + i * 32 + r0;
    if (row >= T_ROWS) row = T_ROWS - 1;   // junk rows masked at store
    aoff[i] = row * KDIM + c16 * 4;
  }
  // A LDS write target (kt-invariant): byte = row*128 + slot'*16 + off8,
  // slot' = (c16>>1) ^ (row&7); row&7 == r0&7 for all i (i*32 % 8 == 0).
  int a_wbyte = r0 * 128 + (((c16 >> 1) ^ (r0 & 7)) << 4) + (c16 & 1) * 8;

  // --- B fallback coords (no-ws path): thread owns n = t>>1, k-half (t&1)*32
  int fb_n = t >> 1, fb_kh = (t & 1) * 32;

  const char* btbase = bt + (((size_t)g) << 20);  // g * 64 * 16384

  f32x4 acc[8][4];
#pragma unroll
  for (int i = 0; i < 8; i++)
#pragma unroll
    for (int j = 0; j < 4; j++) acc[i][j] = (f32x4){0.f, 0.f, 0.f, 0.f};

  f32x4 va[8];

  auto loadA = [&](int kt) {
#pragma unroll
    for (int i = 0; i < 8; i++)
      va[i] = *(const f32x4*)(a + aoff[i] + kt * BK);
  };
  auto writeA = [&](int c) {
    char* db = (char*)lds_a[c] + a_wbyte;
#pragma unroll
    for (int i = 0; i < 8; i++) {
      s16x4 v;
#pragma unroll
      for (int e = 0; e < 4; e++) v[e] = f2bf(va[i][e]);
      *(s16x4*)(db + i * 4096) = v;   // row i*32+r0 -> byte offset i*32*128
    }
  };
  auto stageB_bt = [&](int kt, int c) {
#pragma unroll
    for (int i = 0; i < 4; i++) {
      int wc = wid * 4 + i;                       // wave-chunk 0..31 (uniform)
      int sub = wc >> 4;                          // 0..1 (uniform)
      int cc = (wc & 15) * 64 + lane;             // chunk within sub-image
      const char* gsrc =
          btbase + (((size_t)((bn * 2 + sub) * 16 + kt)) << 14) + cc * 16;
      __builtin_amdgcn_global_load_lds(
          (gbl_u32*)gsrc, (lds_u32*)((char*)lds_b[c] + wc * 1024), 16, 0, 0);
    }
  };
  auto stageB_fb = [&](int kt, int c) {
    const float* p = b + (size_t)g * KDIM * NDIM +
                     (size_t)(kt * BK + fb_kh) * NDIM + bn * BN + fb_n;
    float vals[32];
#pragma unroll
    for (int i = 0; i < 32; i++) vals[i] = p[(size_t)i * NDIM];
    int nn = fb_n & 127;
    char* lb = (char*)lds_b[c] + (fb_n >> 7) * 16384 + nn * 128;
#pragma unroll
    for (int i8 = 0; i8 < 4; i8++) {
      int slot = (fb_kh >> 3) + i8;
      s16x8 v;
#pragma unroll
      for (int e = 0; e < 8; e++) v[e] = f2bf(vals[i8 * 8 + e]);
      *(s16x8*)(lb + (((slot ^ (nn & 7))) << 4)) = v;
    }
  };
  auto compute = [&](int c) {
    const char* As = (const char*)lds_a[c];
    const char* Bs = (const char*)lds_b[c];
#pragma unroll
    for (int ks = 0; ks < 2; ks++) {
      s16x8 af[8], bfr[4];
#pragma unroll
      for (int fm = 0; fm < 8; fm++) {
        int row = wm * 128 + fm * 16 + lr;
        int slot = (ks * 4 + q) ^ (row & 7);
        af[fm] = *(const s16x8*)(As + row * 128 + slot * 16);
      }
#pragma unroll
      for (int fn = 0; fn < 4; fn++) {
        int n = wn * 64 + fn * 16 + lr;
        int slot = (ks * 4 + q) ^ (n & 7);
        bfr[fn] = *(const s16x8*)(Bs + (n >> 7) * 16384 + (n & 127) * 128 +
                                  slot * 16);
      }
      __builtin_amdgcn_s_setprio(1);
#pragma unroll
      for (int fm = 0; fm < 8; fm++)
#pragma unroll
        for (int fn = 0; fn < 4; fn++)
          acc[fm][fn] = __builtin_amdgcn_mfma_f32_16x16x32_bf16(
              af[fm], bfr[fn], acc[fm][fn], 0, 0, 0);
      __builtin_amdgcn_s_setprio(0);
    }
  };

  // prologue
  loadA(0);
  if (USE_BT) stageB_bt(0, 0);
  else stageB_fb(0, 0);
  writeA(0);
  __syncthreads();

  int cur = 0;
  for (int kt = 0; kt < KTILES; kt++) {
    if (kt + 1 < KTILES) {
      loadA(kt + 1);                         // issue next A loads (T14 split)
      if (USE_BT) stageB_bt(kt + 1, cur ^ 1);  // async global->LDS in flight
    }
    compute(cur);
    if (kt + 1 < KTILES) {
      if (!USE_BT) stageB_fb(kt + 1, cur ^ 1);
      writeA(cur ^ 1);                       // vmcnt wait + cvt + ds_write
      __syncthreads();
      cur ^= 1;
    }
  }

  // epilogue: D frag col = lane&15, row = (lane>>4)*4 + j
  size_t orow0 = (size_t)(off + m_loc);
#pragma unroll
  for (int fm = 0; fm < 8; fm++) {
#pragma unroll
    for (int j = 0; j < 4; j++) {
      int rm = wm * 128 + fm * 16 + q * 4 + j;
      if (rm < valid) {
        float* orow = out + (orow0 + rm) * NDIM + bn * BN + wn * 64 + lr;
#pragma unroll
        for (int fn = 0; fn < 4; fn++) orow[fn * 16] = acc[fm][fn][j];
      }
    }
  }
}

extern "C" void kernel_launch(void* const* d_in, const int* in_sizes, int n_in,
                              void* d_out, int out_size, void* d_ws,
                              size_t ws_size, hipStream_t stream) {
  const float* a = (const float*)d_in[0];
  const float* b = (const float*)d_in[1];
  const int* sizes = (const int*)d_in[2];
  const int* offs = (const int*)d_in[3];
  float* out = (float*)d_out;

  const size_t bt_bytes = (size_t)GCNT * KDIM * NDIM * 2;  // 64 MB
  if (ws_size >= bt_bytes) {
    bt_kernel<<<GCNT * 64, 256, 0, stream>>>(b, (char*)d_ws);
    gemm_kernel<true><<<NBLK, 512, 0, stream>>>(a, b, (const char*)d_ws,
                                                sizes, offs, out);
  } else {
    gemm_kernel<false><<<NBLK, 512, 0, stream>>>(a, b, (const char*)nullptr,
                                                 sizes, offs, out);
  }
}

// Round 3
// 307.524 us; speedup vs baseline: 1.7944x; 1.1130x over previous
//
#include <hip/hip_runtime.h>
#include <hip/hip_bf16.h>
#include <stdint.h>

#define T_ROWS 131072
#define GCNT   64
#define KDIM   1024
#define NDIM   512
#define BM     256
#define BN     256
#define BK     64
#define KTILES (KDIM / BK)     // 16
#define MT_MAX 640             // upper bound on 256-row tiles (actual ~550)
#define NBLK   (MT_MAX * 2)    // 1280 blocks, divisible by 8 (XCD swizzle)

typedef __attribute__((ext_vector_type(4))) float f32x4;
typedef __attribute__((ext_vector_type(8))) short s16x8;
typedef __attribute__((ext_vector_type(4))) short s16x4;
typedef __attribute__((address_space(3))) unsigned int lds_u32;
typedef const __attribute__((address_space(1))) unsigned int gbl_u32;

static __device__ __forceinline__ short f2bf(float f) {
  __hip_bfloat16 h = __float2bfloat16(f);
  return __builtin_bit_cast(short, h);
}

// ---------------------------------------------------------------------------
// Pre-pass: b [G][K][N] fp32 -> bt: per (g, nt128, kt) 16KB bf16 tile images,
// layout [G][4][16][16384B]. Image byte for B[k][n] (k in [0,64), n in
// [0,128)):  n*128 + (((k>>3) ^ (n&7))<<4) + (k&7)*2   (bank swizzle baked).
// ---------------------------------------------------------------------------
__global__ __launch_bounds__(256) void bt_kernel(const float* __restrict__ b,
                                                 char* __restrict__ bt) {
  __shared__ short lt[64 * 130];
  int bid = blockIdx.x;               // g*64 + nt*16 + kt
  int kt = bid & 15, nt = (bid >> 4) & 3, g = bid >> 6;
  int t = threadIdx.x;
  const float* src = b + ((size_t)(g * KDIM + kt * BK)) * NDIM + nt * 128;
#pragma unroll
  for (int i = 0; i < 32; i++) {
    int idx = i * 256 + t;
    int kk = idx >> 7, nn = idx & 127;
    lt[kk * 130 + nn] = f2bf(src[(size_t)kk * NDIM + nn]);
  }
  __syncthreads();
  char* dst = bt + ((size_t)bid << 14);
#pragma unroll
  for (int j = 0; j < 4; j++) {
    int chunk = j * 256 + t;
    int n = chunk >> 3;
    int slot = (chunk & 7) ^ (n & 7);
    s16x8 v;
#pragma unroll
    for (int i = 0; i < 8; i++) v[i] = lt[(slot * 8 + i) * 130 + n];
    *(s16x8*)(dst + (size_t)chunk * 16) = v;
  }
}

// ---------------------------------------------------------------------------
// 8-phase grouped GEMM: 256x256 tile, 8 waves (2M x 4N), BK=64, dbuf LDS.
// Per K-tile: 4 {ds_read quadrant | issue prefetch | s_barrier | 16 MFMA}
// phases + 1 stage-commit phase with a single counted vmcnt drain.
// A fp32 issued ph0/ph1 (3-phase cover), B gload_lds ph2/ph3 (2-phase cover).
// ---------------------------------------------------------------------------
__global__ __launch_bounds__(512, 2) void gemm8(
    const float* __restrict__ a, const char* __restrict__ bt,
    const int* __restrict__ sizes, const int* __restrict__ offs,
    float* __restrict__ out) {
  __shared__ __align__(16) short lds_a[2][BM * BK];     // 2 x 32 KB
  __shared__ __align__(16) char lds_b[2][BN * BK * 2];  // 2 x 32 KB

  int bid0 = blockIdx.x;
  int bid = (bid0 & 7) * (NBLK / 8) + (bid0 >> 3);  // XCD-chunked swizzle
  int bn = bid & 1;                                 // A-sharing pair adjacent
  int tm = bid >> 1;

  int g = -1, m_loc = 0, base = 0;
#pragma unroll
  for (int i = 0; i < GCNT; i++) {
    int ps = (sizes[i] + 127) & ~127;
    int tg = (ps + 255) >> 8;
    if (tm >= base && tm < base + tg) { g = i; m_loc = (tm - base) << 8; }
    base += tg;
  }
  if (g < 0) return;
  int size = sizes[g], off = offs[g], valid = size - m_loc;

  int t = threadIdx.x, lane = t & 63, wid = t >> 6;
  int wm = wid >> 2, wn = wid & 3, lr = lane & 15, q = lane >> 4;

  // A staging: thread t owns rows i*32 + (t>>4), fp32 cols (t&15)*4..+3
  int r0 = t >> 4, c16 = t & 15;
  int aoff[8];
#pragma unroll
  for (int i = 0; i < 8; i++) {
    int row = off + m_loc + i * 32 + r0;
    if (row >= T_ROWS) row = T_ROWS - 1;  // junk rows masked at store
    aoff[i] = row * KDIM + c16 * 4;
  }
  int a_wbyte = r0 * 128 + (((c16 >> 1) ^ (r0 & 7)) << 4) + (c16 & 1) * 8;

  const char* btbase = bt + ((size_t)g << 20);

  f32x4 acc[8][4];
#pragma unroll
  for (int i = 0; i < 8; i++)
#pragma unroll
    for (int j = 0; j < 4; j++) acc[i][j] = (f32x4){0.f, 0.f, 0.f, 0.f};
  f32x4 va[8];
  s16x8 af[4], bf0[4], bf1[4];

  auto issueA = [&](int kt, int h) {
#pragma unroll
    for (int i = 0; i < 4; i++)
      va[h * 4 + i] = *(const f32x4*)(a + aoff[h * 4 + i] + kt * BK);
  };
  auto issueB = [&](int kt, int c, int h) {
#pragma unroll
    for (int i = 0; i < 2; i++) {
      int wc = wid * 4 + h * 2 + i;          // wave-uniform chunk id
      int sub = wc >> 4;
      int cc = (wc & 15) * 64 + lane;
      const char* gsrc =
          btbase + (((size_t)((bn * 2 + sub) * 16 + kt)) << 14) + cc * 16;
      __builtin_amdgcn_global_load_lds(
          (gbl_u32*)gsrc, (lds_u32*)((char*)lds_b[c] + wc * 1024), 16, 0, 0);
    }
  };
  auto writeA = [&](int c) {  // compiler auto-waits vmcnt for va
    char* db = (char*)lds_a[c] + a_wbyte;
#pragma unroll
    for (int i = 0; i < 8; i++) {
      s16x4 v;
#pragma unroll
      for (int e = 0; e < 4; e++) v[e] = f2bf(va[i][e]);
      *(s16x4*)(db + i * 4096) = v;
    }
  };
  auto dsA = [&](int c, int half, int ks) {
#pragma unroll
    for (int i = 0; i < 4; i++) {
      int row = wm * 128 + (half * 4 + i) * 16 + lr;
      int slot = (ks * 4 + q) ^ (row & 7);
      af[i] = *(const s16x8*)((const char*)lds_a[c] + row * 128 + slot * 16);
    }
  };
  auto dsB = [&](int c, int ks, s16x8* bf) {
#pragma unroll
    for (int fn = 0; fn < 4; fn++) {
      int n = wn * 64 + fn * 16 + lr;
      int slot = (ks * 4 + q) ^ (n & 7);
      bf[fn] = *(const s16x8*)((const char*)lds_b[c] + (n >> 7) * 16384 +
                               (n & 127) * 128 + slot * 16);
    }
  };
  auto bar = [&]() {
    __builtin_amdgcn_s_barrier();
    __builtin_amdgcn_sched_barrier(0);
  };
  auto mfmaQ = [&](const s16x8* bf, int fmb) {
    __builtin_amdgcn_s_setprio(1);
#pragma unroll
    for (int fm = 0; fm < 4; fm++)
#pragma unroll
      for (int fn = 0; fn < 4; fn++)
        acc[fmb + fm][fn] = __builtin_amdgcn_mfma_f32_16x16x32_bf16(
            af[fm], bf[fn], acc[fmb + fm][fn], 0, 0, 0);
    __builtin_amdgcn_s_setprio(0);
  };

  // prologue: stage tile 0 into buf 0 (A via regs, B via DMA), publish
  issueA(0, 0);
  issueA(0, 1);
  issueB(0, 0, 0);
  issueB(0, 0, 1);
  writeA(0);
  asm volatile("s_waitcnt vmcnt(0) lgkmcnt(0)" ::: "memory");
  bar();

  for (int kt = 0; kt < KTILES; kt++) {
    int cur = kt & 1, nxt = cur ^ 1;
    bool more = (kt + 1 < KTILES);
    // ph0: Q0 = af[0..3]xks0, read bf ks0; issue A(t+1) half0
    dsA(cur, 0, 0);
    dsB(cur, 0, bf0);
    if (more) issueA(kt + 1, 0);
    bar();
    mfmaQ(bf0, 0);
    bar();
    // ph1: Q1 = af[0..3]xks1, read bf ks1; issue A(t+1) half1
    dsA(cur, 0, 1);
    dsB(cur, 1, bf1);
    if (more) issueA(kt + 1, 1);
    bar();
    mfmaQ(bf1, 0);
    bar();
    // ph2: Q2 = af[4..7]xks0 (bf0 reused); issue B(t+1) half0 -> buf nxt
    dsA(cur, 1, 0);
    if (more) issueB(kt + 1, nxt, 0);
    bar();
    mfmaQ(bf0, 4);
    bar();
    // ph3: Q3 = af[4..7]xks1 (bf1 reused); issue B(t+1) half1
    dsA(cur, 1, 1);
    if (more) issueB(kt + 1, nxt, 1);
    bar();
    mfmaQ(bf1, 4);
    bar();
    // ph4: commit A(t+1) to LDS, publish DMA + ds_writes, flip buffers
    if (more) {
      writeA(nxt);
      asm volatile("s_waitcnt vmcnt(0) lgkmcnt(0)" ::: "memory");
      bar();
    }
  }

  // epilogue: D frag col = lane&15, row = (lane>>4)*4 + j; masked rows
  size_t orow0 = (size_t)(off + m_loc);
#pragma unroll
  for (int fm = 0; fm < 8; fm++) {
#pragma unroll
    for (int j = 0; j < 4; j++) {
      int rm = wm * 128 + fm * 16 + q * 4 + j;
      if (rm < valid) {
        float* orow = out + (orow0 + rm) * NDIM + bn * BN + wn * 64 + lr;
#pragma unroll
        for (int fn = 0; fn < 4; fn++) orow[fn * 16] = acc[fm][fn][j];
      }
    }
  }
}

// ---------------------------------------------------------------------------
// Fallback (no workspace): round-2 2-phase kernel, B transposed in-kernel.
// ---------------------------------------------------------------------------
__global__ __launch_bounds__(512, 2) void gemm_fb(
    const float* __restrict__ a, const float* __restrict__ b,
    const int* __restrict__ sizes, const int* __restrict__ offs,
    float* __restrict__ out) {
  __shared__ __align__(16) short lds_a[2][BM * BK];
  __shared__ __align__(16) char lds_b[2][BN * BK * 2];

  int bid0 = blockIdx.x;
  int bid = (bid0 & 7) * (NBLK / 8) + (bid0 >> 3);
  int bn = bid & 1;
  int tm = bid >> 1;

  int g = -1, m_loc = 0, base = 0;
#pragma unroll
  for (int i = 0; i < GCNT; i++) {
    int ps = (sizes[i] + 127) & ~127;
    int tg = (ps + 255) >> 8;
    if (tm >= base && tm < base + tg) { g = i; m_loc = (tm - base) << 8; }
    base += tg;
  }
  if (g < 0) return;
  int size = sizes[g], off = offs[g], valid = size - m_loc;

  int t = threadIdx.x, lane = t & 63, wid = t >> 6;
  int wm = wid >> 2, wn = wid & 3, lr = lane & 15, q = lane >> 4;

  int r0 = t >> 4, c16 = t & 15;
  int aoff[8];
#pragma unroll
  for (int i = 0; i < 8; i++) {
    int row = off + m_loc + i * 32 + r0;
    if (row >= T_ROWS) row = T_ROWS - 1;
    aoff[i] = row * KDIM + c16 * 4;
  }
  int a_wbyte = r0 * 128 + (((c16 >> 1) ^ (r0 & 7)) << 4) + (c16 & 1) * 8;
  int fb_n = t >> 1, fb_kh = (t & 1) * 32;

  f32x4 acc[8][4];
#pragma unroll
  for (int i = 0; i < 8; i++)
#pragma unroll
    for (int j = 0; j < 4; j++) acc[i][j] = (f32x4){0.f, 0.f, 0.f, 0.f};
  f32x4 va[8];

  auto loadA = [&](int kt) {
#pragma unroll
    for (int i = 0; i < 8; i++) va[i] = *(const f32x4*)(a + aoff[i] + kt * BK);
  };
  auto writeA = [&](int c) {
    char* db = (char*)lds_a[c] + a_wbyte;
#pragma unroll
    for (int i = 0; i < 8; i++) {
      s16x4 v;
#pragma unroll
      for (int e = 0; e < 4; e++) v[e] = f2bf(va[i][e]);
      *(s16x4*)(db + i * 4096) = v;
    }
  };
  auto stageB = [&](int kt, int c) {
    const float* p = b + (size_t)g * KDIM * NDIM +
                     (size_t)(kt * BK + fb_kh) * NDIM + bn * BN + fb_n;
    float vals[32];
#pragma unroll
    for (int i = 0; i < 32; i++) vals[i] = p[(size_t)i * NDIM];
    int nn = fb_n & 127;
    char* lb = (char*)lds_b[c] + (fb_n >> 7) * 16384 + nn * 128;
#pragma unroll
    for (int i8 = 0; i8 < 4; i8++) {
      int slot = (fb_kh >> 3) + i8;
      s16x8 v;
#pragma unroll
      for (int e = 0; e < 8; e++) v[e] = f2bf(vals[i8 * 8 + e]);
      *(s16x8*)(lb + (((slot ^ (nn & 7))) << 4)) = v;
    }
  };
  auto compute = [&](int c) {
#pragma unroll
    for (int ks = 0; ks < 2; ks++) {
      s16x8 af[8], bfr[4];
#pragma unroll
      for (int fm = 0; fm < 8; fm++) {
        int row = wm * 128 + fm * 16 + lr;
        int slot = (ks * 4 + q) ^ (row & 7);
        af[fm] = *(const s16x8*)((const char*)lds_a[c] + row * 128 + slot * 16);
      }
#pragma unroll
      for (int fn = 0; fn < 4; fn++) {
        int n = wn * 64 + fn * 16 + lr;
        int slot = (ks * 4 + q) ^ (n & 7);
        bfr[fn] = *(const s16x8*)((const char*)lds_b[c] + (n >> 7) * 16384 +
                                  (n & 127) * 128 + slot * 16);
      }
#pragma unroll
      for (int fm = 0; fm < 8; fm++)
#pragma unroll
        for (int fn = 0; fn < 4; fn++)
          acc[fm][fn] = __builtin_amdgcn_mfma_f32_16x16x32_bf16(
              af[fm], bfr[fn], acc[fm][fn], 0, 0, 0);
    }
  };

  loadA(0);
  stageB(0, 0);
  writeA(0);
  __syncthreads();
  int cur = 0;
  for (int kt = 0; kt < KTILES; kt++) {
    if (kt + 1 < KTILES) loadA(kt + 1);
    compute(cur);
    if (kt + 1 < KTILES) {
      stageB(kt + 1, cur ^ 1);
      writeA(cur ^ 1);
      __syncthreads();
      cur ^= 1;
    }
  }
  size_t orow0 = (size_t)(off + m_loc);
#pragma unroll
  for (int fm = 0; fm < 8; fm++) {
#pragma unroll
    for (int j = 0; j < 4; j++) {
      int rm = wm * 128 + fm * 16 + q * 4 + j;
      if (rm < valid) {
        float* orow = out + (orow0 + rm) * NDIM + bn * BN + wn * 64 + lr;
#pragma unroll
        for (int fn = 0; fn < 4; fn++) orow[fn * 16] = acc[fm][fn][j];
      }
    }
  }
}

extern "C" void kernel_launch(void* const* d_in, const int* in_sizes, int n_in,
                              void* d_out, int out_size, void* d_ws,
                              size_t ws_size, hipStream_t stream) {
  const float* a = (const float*)d_in[0];
  const float* b = (const float*)d_in[1];
  const int* sizes = (const int*)d_in[2];
  const int* offs = (const int*)d_in[3];
  float* out = (float*)d_out;

  const size_t bt_bytes = (size_t)GCNT * KDIM * NDIM * 2;  // 64 MB
  if (ws_size >= bt_bytes) {
    bt_kernel<<<GCNT * 64, 256, 0, stream>>>(b, (char*)d_ws);
    gemm8<<<NBLK, 512, 0, stream>>>(a, (const char*)d_ws, sizes, offs, out);
  } else {
    gemm_fb<<<NBLK, 512, 0, stream>>>(a, b, sizes, offs, out);
  }
}